// Round 18
// baseline (63.369 us; speedup 1.0000x reference)
//
#include <hip/hip_runtime.h>
#include <hip/hip_bf16.h>
#include <math.h>

#define CIN   64
#define COUT  32
#define K1V   17
#define HV    4
#define BTILE 3           // bt slices per gcn block (24 = 8 tiles x 3)

typedef float v4f __attribute__((ext_vector_type(4)));
typedef unsigned int v4u __attribute__((ext_vector_type(4)));
typedef short bf8s __attribute__((ext_vector_type(8)));   // 8 bf16 = 4 VGPRs (MFMA A/B frag)
typedef float f32x16 __attribute__((ext_vector_type(16)));
typedef unsigned short u16;

__device__ __forceinline__ float bf2f(u16 h) {
  unsigned u = ((unsigned)h) << 16;
  return __builtin_bit_cast(float, u);
}
__device__ __forceinline__ unsigned cvt2(float lo, float hi) {
  __hip_bfloat162 p = __float22bfloat162_rn(make_float2(lo, hi));
  unsigned u;
  __builtin_memcpy(&u, &p, 4);
  return u;
}
__device__ __forceinline__ bf8s pack8(v4f a, v4f b) {
  v4u u = { cvt2(a.x, a.y), cvt2(a.z, a.w), cvt2(b.x, b.y), cvt2(b.z, b.w) };
  return __builtin_bit_cast(bf8s, u);
}
__device__ __forceinline__ u16 f2bf(float f) {
  __hip_bfloat16 h = __float2bfloat16(f);
  u16 u;
  __builtin_memcpy(&u, &h, 2);
  return u;
}

// Kernel A (MFMA, zero-LDS, 2 tiles/wave): xp16[r,o]=bf16(x[r,:]*W[o,:]+b[o])
// Each wave computes TWO 32x32 tiles (64 rows): all 24 b128 loads issued
// up-front (deep MLP to cover HBM latency), then 8x mfma_f32_32x32x16_bf16.
// launch_bounds(256,2): ~150-reg peak, no spill; 8 waves/CU x 24 loads.
// C/D (m74/m101): col=lane&31, row=(reg&3)+8*(reg>>2)+4*(lane>>5).
__global__ __launch_bounds__(256, 2) void proj_kernel(
    const float* __restrict__ x, const float* __restrict__ W,
    const float* __restrict__ b, u16* __restrict__ xp, long nrows) {
  int tid = threadIdx.x;
  int wv  = tid >> 6;
  int l   = tid & 63;
  int lr  = l & 31;
  int lh  = l >> 5;
  long rbase = (long)blockIdx.x * 256 + wv * 64;   // 240000 % 64 == 0
  if (rbase >= nrows) return;

  const float* xrA = x + (rbase + lr) * CIN + lh * 8;
  const float* xrB = xrA + 32 * CIN;
  const float* wr  = W + (long)lr * CIN + lh * 8;

  v4f xa[8], xb[8], wl_[8];
#pragma unroll
  for (int ks = 0; ks < 4; ++ks) {
    xa[2*ks]   = *(const v4f*)(xrA + ks * 16);
    xa[2*ks+1] = *(const v4f*)(xrA + ks * 16 + 4);
    xb[2*ks]   = *(const v4f*)(xrB + ks * 16);
    xb[2*ks+1] = *(const v4f*)(xrB + ks * 16 + 4);
    wl_[2*ks]   = *(const v4f*)(wr + ks * 16);
    wl_[2*ks+1] = *(const v4f*)(wr + ks * 16 + 4);
  }

  f32x16 accA, accB;
#pragma unroll
  for (int i = 0; i < 16; ++i) { accA[i] = 0.0f; accB[i] = 0.0f; }

#pragma unroll
  for (int ks = 0; ks < 4; ++ks) {
    bf8s bfr = pack8(wl_[2*ks], wl_[2*ks+1]);
    accA = __builtin_amdgcn_mfma_f32_32x32x16_bf16(
        pack8(xa[2*ks], xa[2*ks+1]), bfr, accA, 0, 0, 0);
    accB = __builtin_amdgcn_mfma_f32_32x32x16_bf16(
        pack8(xb[2*ks], xb[2*ks+1]), bfr, accB, 0, 0, 0);
  }

  float bias = b[lr];
  u16* outA = xp + rbase * COUT;
  u16* outB = xp + (rbase + 32) * COUT;
#pragma unroll
  for (int r = 0; r < 16; ++r) {
    int rr = (r & 3) + 8 * (r >> 2) + 4 * lh;
    outA[(size_t)rr * COUT + lr] = f2bf(accA[r] + bias);
    outB[(size_t)rr * COUT + lr] = f2bf(accB[r] + bias);
  }
}

// Kernel C (R15 best: R5 structure + BTILE=3): grid (node_groups, BT/3), x
// fastest -> co-resident blocks share a 1.92MB 3-slice window (fits XCD L2).
// Table built once per block; per k: 3 independent gathers feed 12 FMAs;
// 12 nt stores.
__global__ __launch_bounds__(256) void gcn_kernel(
    const u16*   __restrict__ xp,    // (BT, N, 32) bf16
    const float* __restrict__ dist,  // (N, K1)
    const int*   __restrict__ nn,    // (N, K1)
    float* __restrict__ out,         // (BT, N, H, 32)
    int N) {
  __shared__ float wl[8][K1V][HV];
  __shared__ float dl[8][K1V];
  __shared__ int   nl[8][K1V];
  __shared__ float dagl[8][HV];

  int tid = threadIdx.x;
  int bt0 = blockIdx.y * BTILE;
  int n0  = blockIdx.x * 8;

  if (tid < 8 * K1V) {        // 136 builder threads
    int l = tid / K1V, k = tid % K1V;
    int n_ = n0 + l;
    float w0 = 0, w1 = 0, w2 = 0, w3 = 0, dc = 0;
    int idx = 0;
    if (n_ < N) {
      float d = dist[(long)n_ * K1V + k];
      idx = nn[(long)n_ * K1V + k];
      float d2 = d * d;
      w0 = __expf(-d2 * 0.25f);
      w1 = __expf(-d2 * 0.50f);
      w2 = __expf(-d2 * 0.75f);
      w3 = __expf(-d2);
      if (idx == -1) { w0 = w1 = w2 = w3 = 0.0f; }
      if (w0 < 1e-5f) w0 = 0.0f;
      if (w1 < 1e-5f) w1 = 0.0f;
      if (w2 < 1e-5f) w2 = 0.0f;
      if (w3 < 1e-5f) w3 = 0.0f;
      dc = isinf(d) ? 0.0f : d;
      if (idx < 0 || idx >= N) idx = 0;   // its w==0; safe address
    }
    wl[l][k][0] = w0; wl[l][k][1] = w1; wl[l][k][2] = w2; wl[l][k][3] = w3;
    dl[l][k] = dc; nl[l][k] = idx;
  }
  __syncthreads();

  if (tid < 8 * HV) {         // fold dist_agg once per (node, head)
    int l = tid >> 2, h = tid & 3;
    float s = 0.0f;
#pragma unroll
    for (int k = 0; k < K1V; ++k) s = fmaf(wl[l][k][h], dl[l][k], s);
    dagl[l][h] = s;
  }
  __syncthreads();

  int ln = tid >> 5;          // local node
  int c  = tid & 31;          // channel
  int n  = n0 + ln;
  if (n >= N) return;

  int off[K1V];               // element offsets within a slice
#pragma unroll
  for (int k = 0; k < K1V; ++k) off[k] = nl[ln][k] * COUT;

  const int SL = N * COUT;    // elements per slice
  const u16* base = xp + (size_t)bt0 * SL + c;

  float a[BTILE][HV];
#pragma unroll
  for (int t = 0; t < BTILE; ++t) {
    a[t][0] = dagl[ln][0]; a[t][1] = dagl[ln][1];
    a[t][2] = dagl[ln][2]; a[t][3] = dagl[ln][3];
  }

#pragma unroll
  for (int k = 0; k < K1V; ++k) {
    float v0 = bf2f(base[off[k]]);
    float v1 = bf2f(base[off[k] + SL]);
    float v2 = bf2f(base[off[k] + 2 * SL]);
    v4f w4 = *(const v4f*)&wl[ln][k][0];
    a[0][0] = fmaf(w4.x, v0, a[0][0]);
    a[0][1] = fmaf(w4.y, v0, a[0][1]);
    a[0][2] = fmaf(w4.z, v0, a[0][2]);
    a[0][3] = fmaf(w4.w, v0, a[0][3]);
    a[1][0] = fmaf(w4.x, v1, a[1][0]);
    a[1][1] = fmaf(w4.y, v1, a[1][1]);
    a[1][2] = fmaf(w4.z, v1, a[1][2]);
    a[1][3] = fmaf(w4.w, v1, a[1][3]);
    a[2][0] = fmaf(w4.x, v2, a[2][0]);
    a[2][1] = fmaf(w4.y, v2, a[2][1]);
    a[2][2] = fmaf(w4.z, v2, a[2][2]);
    a[2][3] = fmaf(w4.w, v2, a[2][3]);
  }

#pragma unroll
  for (int t = 0; t < BTILE; ++t) {
    float* ob = out + (((size_t)(bt0 + t) * N + n) * HV) * COUT + c;
    __builtin_nontemporal_store(a[t][0], ob);
    __builtin_nontemporal_store(a[t][1], ob + COUT);
    __builtin_nontemporal_store(a[t][2], ob + 2 * COUT);
    __builtin_nontemporal_store(a[t][3], ob + 3 * COUT);
  }
}

extern "C" void kernel_launch(void* const* d_in, const int* in_sizes, int n_in,
                              void* d_out, int out_size, void* d_ws, size_t ws_size,
                              hipStream_t stream) {
  const float* x    = (const float*)d_in[0];
  const float* W    = (const float*)d_in[1];
  const float* b    = (const float*)d_in[2];
  const float* dist = (const float*)d_in[3];
  const int*   nn   = (const int*)d_in[4];
  float* out = (float*)d_out;
  u16*   xp  = (u16*)d_ws;     // (BT, N, 32) bf16 = 15.36 MB

  int  N  = in_sizes[4] / K1V;                 // 10000
  long M  = (long)in_sizes[0] / CIN;           // BT * N = 240000
  int  BT = (int)(M / N);                      // 24

  proj_kernel<<<(int)((M + 255) / 256), 256, 0, stream>>>(x, W, b, xp, M);

  dim3 grid((N + 7) / 8, BT / BTILE);          // 1250 x 8, x fastest
  gcn_kernel<<<grid, 256, 0, stream>>>(xp, dist, nn, out, N);
}

// Round 19
// 61.921 us; speedup vs baseline: 1.0234x; 1.0234x over previous
//
#include <hip/hip_runtime.h>
#include <hip/hip_bf16.h>
#include <math.h>

#define CIN   64
#define COUT  32
#define K1V   17
#define HV    4
#define BTILE 3           // bt slices per gcn block (24 = 8 tiles x 3)

typedef float v4f __attribute__((ext_vector_type(4)));
typedef unsigned int v4u __attribute__((ext_vector_type(4)));
typedef short bf8s __attribute__((ext_vector_type(8)));   // 8 bf16 = 4 VGPRs (MFMA A/B frag)
typedef float f32x16 __attribute__((ext_vector_type(16)));
typedef unsigned short u16;

__device__ __forceinline__ float bf2f(u16 h) {
  unsigned u = ((unsigned)h) << 16;
  return __builtin_bit_cast(float, u);
}
__device__ __forceinline__ unsigned cvt2(float lo, float hi) {
  __hip_bfloat162 p = __float22bfloat162_rn(make_float2(lo, hi));
  unsigned u;
  __builtin_memcpy(&u, &p, 4);
  return u;
}
__device__ __forceinline__ bf8s pack8(v4f a, v4f b) {
  v4u u = { cvt2(a.x, a.y), cvt2(a.z, a.w), cvt2(b.x, b.y), cvt2(b.z, b.w) };
  return __builtin_bit_cast(bf8s, u);
}
__device__ __forceinline__ u16 f2bf(float f) {
  __hip_bfloat16 h = __float2bfloat16(f);
  u16 u;
  __builtin_memcpy(&u, &h, 2);
  return u;
}

// Kernel A (MFMA, zero-LDS, R15 1-tile form): computes x[r,:]*W[o,:]+b[o],
// stores bf16 into the TILE-INTERLEAVED layout:
//   xp2[((j*N + n)*3 + t)*32 + o],  where bt = j*3 + t, r = bt*N + n.
// So the 3 bt-slices of one node's row are 192B contiguous -> gcn's
// triple-gather per k hits one 2-line neighborhood (L1 reuse, less fetch).
// C/D (m74/m101): col=lane&31, row=(reg&3)+8*(reg>>2)+4*(lane>>5).
__global__ __launch_bounds__(256, 4) void proj_kernel(
    const float* __restrict__ x, const float* __restrict__ W,
    const float* __restrict__ b, u16* __restrict__ xp, long nrows, int N) {
  int tid = threadIdx.x;
  int wv  = tid >> 6;
  int l   = tid & 63;
  int lr  = l & 31;
  int lh  = l >> 5;
  long rbase = (long)blockIdx.x * 128 + wv * 32;   // M = 240000 = 1875*128
  if (rbase + lr >= nrows) return;

  const float* xr = x + (rbase + lr) * CIN + lh * 8;
  const float* wr = W + (long)lr * CIN + lh * 8;

  bf8s afr[4], bfr[4];
#pragma unroll
  for (int ks = 0; ks < 4; ++ks) {
    v4f xa = *(const v4f*)(xr + ks * 16);
    v4f xb = *(const v4f*)(xr + ks * 16 + 4);
    v4f wa = *(const v4f*)(wr + ks * 16);
    v4f wb = *(const v4f*)(wr + ks * 16 + 4);
    afr[ks] = pack8(xa, xb);
    bfr[ks] = pack8(wa, wb);
  }

  f32x16 acc;
#pragma unroll
  for (int i = 0; i < 16; ++i) acc[i] = 0.0f;
#pragma unroll
  for (int ks = 0; ks < 4; ++ks)
    acc = __builtin_amdgcn_mfma_f32_32x32x16_bf16(afr[ks], bfr[ks], acc, 0, 0, 0);

  float bias = b[lr];
  int bt0  = (int)(rbase / N);
  int rem0 = (int)(rbase - (long)bt0 * N);
#pragma unroll
  for (int r = 0; r < 16; ++r) {
    int rr = (r & 3) + 8 * (r >> 2) + 4 * lh;   // row within 32-row tile
    int n  = rem0 + rr;
    int bt = bt0;
    if (n >= N) { n -= N; bt += 1; }            // tile may straddle one bt edge
    int j  = (bt * 21846) >> 16;                // bt/3, exact for bt < 24
    int t  = bt - 3 * j;
    size_t off = ((size_t)((long)j * N + n) * 3 + t) * 32 + lr;
    xp[off] = f2bf(acc[r] + bias);              // 32 lanes -> 64B contiguous
  }
}

// Kernel C (R15 structure + interleaved xp): grid (node_groups, 8 tiles).
// Per k: 3 gathers land within one 192B contiguous node-row (v1/v2 L1-hit),
// feed 12 FMAs; 12 nt stores.
__global__ __launch_bounds__(256) void gcn_kernel(
    const u16*   __restrict__ xp,    // (8, N, 3, 32) bf16 interleaved
    const float* __restrict__ dist,  // (N, K1)
    const int*   __restrict__ nn,    // (N, K1)
    float* __restrict__ out,         // (BT, N, H, 32)
    int N) {
  __shared__ float wl[8][K1V][HV];
  __shared__ float dl[8][K1V];
  __shared__ int   nl[8][K1V];
  __shared__ float dagl[8][HV];

  int tid = threadIdx.x;
  int jt  = blockIdx.y;            // bt tile: bt = jt*3 + t
  int bt0 = jt * BTILE;
  int n0  = blockIdx.x * 8;

  if (tid < 8 * K1V) {        // 136 builder threads
    int l = tid / K1V, k = tid % K1V;
    int n_ = n0 + l;
    float w0 = 0, w1 = 0, w2 = 0, w3 = 0, dc = 0;
    int idx = 0;
    if (n_ < N) {
      float d = dist[(long)n_ * K1V + k];
      idx = nn[(long)n_ * K1V + k];
      float d2 = d * d;
      w0 = __expf(-d2 * 0.25f);
      w1 = __expf(-d2 * 0.50f);
      w2 = __expf(-d2 * 0.75f);
      w3 = __expf(-d2);
      if (idx == -1) { w0 = w1 = w2 = w3 = 0.0f; }
      if (w0 < 1e-5f) w0 = 0.0f;
      if (w1 < 1e-5f) w1 = 0.0f;
      if (w2 < 1e-5f) w2 = 0.0f;
      if (w3 < 1e-5f) w3 = 0.0f;
      dc = isinf(d) ? 0.0f : d;
      if (idx < 0 || idx >= N) idx = 0;   // its w==0; safe address
    }
    wl[l][k][0] = w0; wl[l][k][1] = w1; wl[l][k][2] = w2; wl[l][k][3] = w3;
    dl[l][k] = dc; nl[l][k] = idx;
  }
  __syncthreads();

  if (tid < 8 * HV) {         // fold dist_agg once per (node, head)
    int l = tid >> 2, h = tid & 3;
    float s = 0.0f;
#pragma unroll
    for (int k = 0; k < K1V; ++k) s = fmaf(wl[l][k][h], dl[l][k], s);
    dagl[l][h] = s;
  }
  __syncthreads();

  int ln = tid >> 5;          // local node
  int c  = tid & 31;          // channel
  int n  = n0 + ln;
  if (n >= N) return;

  int off[K1V];               // element offsets within this tile's xp block
#pragma unroll
  for (int k = 0; k < K1V; ++k) off[k] = nl[ln][k] * (BTILE * COUT);

  const u16* base = xp + (size_t)jt * N * (BTILE * COUT) + c;

  float a[BTILE][HV];
#pragma unroll
  for (int t = 0; t < BTILE; ++t) {
    a[t][0] = dagl[ln][0]; a[t][1] = dagl[ln][1];
    a[t][2] = dagl[ln][2]; a[t][3] = dagl[ln][3];
  }

#pragma unroll
  for (int k = 0; k < K1V; ++k) {
    float v0 = bf2f(base[off[k]]);          // same 192B node-row:
    float v1 = bf2f(base[off[k] + COUT]);   //   v1, v2 are L1 hits
    float v2 = bf2f(base[off[k] + 2 * COUT]);
    v4f w4 = *(const v4f*)&wl[ln][k][0];
    a[0][0] = fmaf(w4.x, v0, a[0][0]);
    a[0][1] = fmaf(w4.y, v0, a[0][1]);
    a[0][2] = fmaf(w4.z, v0, a[0][2]);
    a[0][3] = fmaf(w4.w, v0, a[0][3]);
    a[1][0] = fmaf(w4.x, v1, a[1][0]);
    a[1][1] = fmaf(w4.y, v1, a[1][1]);
    a[1][2] = fmaf(w4.z, v1, a[1][2]);
    a[1][3] = fmaf(w4.w, v1, a[1][3]);
    a[2][0] = fmaf(w4.x, v2, a[2][0]);
    a[2][1] = fmaf(w4.y, v2, a[2][1]);
    a[2][2] = fmaf(w4.z, v2, a[2][2]);
    a[2][3] = fmaf(w4.w, v2, a[2][3]);
  }

#pragma unroll
  for (int t = 0; t < BTILE; ++t) {
    float* ob = out + (((size_t)(bt0 + t) * N + n) * HV) * COUT + c;
    __builtin_nontemporal_store(a[t][0], ob);
    __builtin_nontemporal_store(a[t][1], ob + COUT);
    __builtin_nontemporal_store(a[t][2], ob + 2 * COUT);
    __builtin_nontemporal_store(a[t][3], ob + 3 * COUT);
  }
}

extern "C" void kernel_launch(void* const* d_in, const int* in_sizes, int n_in,
                              void* d_out, int out_size, void* d_ws, size_t ws_size,
                              hipStream_t stream) {
  const float* x    = (const float*)d_in[0];
  const float* W    = (const float*)d_in[1];
  const float* b    = (const float*)d_in[2];
  const float* dist = (const float*)d_in[3];
  const int*   nn   = (const int*)d_in[4];
  float* out = (float*)d_out;
  u16*   xp  = (u16*)d_ws;     // (8, N, 3, 32) bf16 = 15.36 MB

  int  N  = in_sizes[4] / K1V;                 // 10000
  long M  = (long)in_sizes[0] / CIN;           // BT * N = 240000
  int  BT = (int)(M / N);                      // 24

  proj_kernel<<<(int)((M + 127) / 128), 256, 0, stream>>>(x, W, b, xp, M, N);

  dim3 grid((N + 7) / 8, BT / BTILE);          // 1250 x 8, x fastest
  gcn_kernel<<<grid, 256, 0, stream>>>(xp, dist, nn, out, N);
}